// Round 3
// baseline (664.663 us; speedup 1.0000x reference)
//
#include <hip/hip_runtime.h>
#include <hip/hip_bf16.h>

#define BB 32
#define LL 12
#define NN 1024
#define FF 2
#define HH 128
#define HORN 12
#define G3 384

typedef unsigned short u16;
typedef unsigned int u32;
typedef __attribute__((ext_vector_type(8))) short short8;
typedef __attribute__((ext_vector_type(4))) float f32x4;

__device__ __forceinline__ u16 to_bf16(float f) {
    return __builtin_bit_cast(u16, __float2bfloat16(f));
}

// ---- A fp32 [1024][1024] -> bf16 ----
__global__ void prep_abf(const float* __restrict__ A, u16* __restrict__ Abf) {
    int t = blockIdx.x * blockDim.x + threadIdx.x;
    float4 v = ((const float4*)A)[t];
    ushort4 o;
    o.x = to_bf16(v.x); o.y = to_bf16(v.y); o.z = to_bf16(v.z); o.w = to_bf16(v.w);
    ((ushort4*)Abf)[t] = o;
}

// ---- W_h [128][384] fp32 -> W_hT [384][128] bf16 ----
__global__ void prep_whT(const float* __restrict__ W_h, u16* __restrict__ whT) {
    int t = blockIdx.x * blockDim.x + threadIdx.x;
    if (t >= HH * G3) return;
    int c = t / HH, k = t % HH;
    whT[c * HH + k] = to_bf16(W_h[k * G3 + c]);
}

// ---- one GRU step ----
// block: batch b, rows [i0,i0+64). 512 thr = 8 waves (2m x 4n of 32x32 tiles).
// GEMM1: A staged in LDS (dbuf, 1 barrier/chunk); B (hT) streamed L2->reg.
__global__ __launch_bounds__(512, 4) void gru_step(
    const u16* __restrict__ Abf, const u16* __restrict__ hT_old,
    const float* __restrict__ h_old, float* __restrict__ h_new,
    u16* __restrict__ hT_new, const u16* __restrict__ whT,
    const float* __restrict__ x, const float* __restrict__ W_x,
    const float* __restrict__ b_x, const float* __restrict__ b_h, int t) {
    // LDS: A dbuf 2x8K @0 | Ah [64][256B] @16384 | T [128][128B] @32768  = 48K
    __shared__ __align__(16) char smem[49152];

    int bid = blockIdx.x;
    int swz = (bid & 7) * 64 + (bid >> 3);  // 64 consecutive per XCD -> 4 b/XCD in L2
    int b = swz >> 4;
    int i0 = (swz & 15) * 64;
    int tid = threadIdx.x;
    int w = tid >> 6, lane = tid & 63;
    int lcol = lane & 15, kgrp = lane >> 4;
    int wm = w >> 2, wn = w & 3;

    // ---- A staging mapping (uint4 per thread per chunk) ----
    int a_lr = tid >> 3;                   // row 0..63
    int a_c8 = (tid & 7) * 8;              // elem col within 64-col chunk
    const u16* a_src = Abf + (size_t)(i0 + a_lr) * 1024 + a_c8;
    u32 a_wo = (u32)(a_lr * 128 + ((a_c8 * 2) ^ ((a_lr & 7) << 4)));

    // ---- GEMM1 frag addresses ----
    int ar = wm * 32 + lcol;               // A-frag row (mt=0); mt=1 -> +16 (same swz bits)
    u32 ab0 = (u32)(ar * 128);
    u32 aswz = (u32)((ar & 7) << 4);
    const u16* pB0 = hT_old + (size_t)b * 131072 + (size_t)(wn * 32 + lcol) * 1024 + kgrp * 8;
    const u16* pB1 = pB0 + 16 * 1024;

    f32x4 acc[2][2] = {{{0.f,0.f,0.f,0.f},{0.f,0.f,0.f,0.f}},
                       {{0.f,0.f,0.f,0.f},{0.f,0.f,0.f,0.f}}};

    // prologue: chunk 0 staged + B chunk 0 prefetched
    uint4 ra = *(const uint4*)a_src;
    *(uint4*)(smem + a_wo) = ra;
    uint4 bq0 = *(const uint4*)pB0;
    uint4 bq1 = *(const uint4*)pB1;
    uint4 bq2 = *(const uint4*)(pB0 + 32);
    uint4 bq3 = *(const uint4*)(pB1 + 32);

    for (int c16 = 0; c16 < 16; ++c16) {
        __syncthreads();
        uint4 ra2, nb0, nb1, nb2, nb3;
        bool pf = (c16 < 15);
        if (pf) {
            int o = (c16 + 1) * 64;
            ra2 = *(const uint4*)(a_src + o);
            nb0 = *(const uint4*)(pB0 + o);
            nb1 = *(const uint4*)(pB1 + o);
            nb2 = *(const uint4*)(pB0 + o + 32);
            nb3 = *(const uint4*)(pB1 + o + 32);
        }
        u32 abase = (u32)((c16 & 1) * 8192) + ab0;
        // ks = 0
        {
            u32 kb = (u32)(kgrp * 16);
            short8 af0 = *(const short8*)(smem + abase + (kb ^ aswz));
            short8 af1 = *(const short8*)(smem + abase + 2048 + (kb ^ aswz));
            acc[0][0] = __builtin_amdgcn_mfma_f32_16x16x32_bf16(af0, __builtin_bit_cast(short8, bq0), acc[0][0], 0, 0, 0);
            acc[0][1] = __builtin_amdgcn_mfma_f32_16x16x32_bf16(af0, __builtin_bit_cast(short8, bq1), acc[0][1], 0, 0, 0);
            acc[1][0] = __builtin_amdgcn_mfma_f32_16x16x32_bf16(af1, __builtin_bit_cast(short8, bq0), acc[1][0], 0, 0, 0);
            acc[1][1] = __builtin_amdgcn_mfma_f32_16x16x32_bf16(af1, __builtin_bit_cast(short8, bq1), acc[1][1], 0, 0, 0);
        }
        // ks = 1
        {
            u32 kb = (u32)(64 + kgrp * 16);
            short8 af0 = *(const short8*)(smem + abase + (kb ^ aswz));
            short8 af1 = *(const short8*)(smem + abase + 2048 + (kb ^ aswz));
            acc[0][0] = __builtin_amdgcn_mfma_f32_16x16x32_bf16(af0, __builtin_bit_cast(short8, bq2), acc[0][0], 0, 0, 0);
            acc[0][1] = __builtin_amdgcn_mfma_f32_16x16x32_bf16(af0, __builtin_bit_cast(short8, bq3), acc[0][1], 0, 0, 0);
            acc[1][0] = __builtin_amdgcn_mfma_f32_16x16x32_bf16(af1, __builtin_bit_cast(short8, bq2), acc[1][0], 0, 0, 0);
            acc[1][1] = __builtin_amdgcn_mfma_f32_16x16x32_bf16(af1, __builtin_bit_cast(short8, bq3), acc[1][1], 0, 0, 0);
        }
        if (pf) {
            *(uint4*)(smem + ((c16 + 1) & 1) * 8192 + a_wo) = ra2;
            bq0 = nb0; bq1 = nb1; bq2 = nb2; bq3 = nb3;
        }
    }

    // ---- Ah -> LDS (bf16, swizzled [64 rows][256 B]) ----
#pragma unroll
    for (int mt = 0; mt < 2; ++mt) {
#pragma unroll
        for (int nt = 0; nt < 2; ++nt) {
#pragma unroll
            for (int ri = 0; ri < 4; ++ri) {
                int row = wm * 32 + mt * 16 + kgrp * 4 + ri;
                int col = wn * 32 + nt * 16 + lcol;
                *(u16*)(smem + 16384 + row * 256 + ((2 * col) ^ ((row & 7) << 4))) = to_bf16(acc[mt][nt][ri]);
            }
        }
    }
    __syncthreads();

    // ---- GEMM2: gates = Ah @ W_h; wave owns hh-tile [w*16,w*16+16) x 3 gates ----
    int hh = w * 16 + lcol;
    f32x4 acc2[4][3];
#pragma unroll
    for (int rt = 0; rt < 4; ++rt)
#pragma unroll
        for (int g = 0; g < 3; ++g) acc2[rt][g] = (f32x4){0.f, 0.f, 0.f, 0.f};

#pragma unroll
    for (int g = 0; g < 3; ++g) {
        short8 bw[4];
#pragma unroll
        for (int ks = 0; ks < 4; ++ks)
            bw[ks] = *(const short8*)(whT + (size_t)(g * 128 + hh) * 128 + ks * 32 + kgrp * 8);
#pragma unroll
        for (int rt = 0; rt < 4; ++rt) {
            int r2 = rt * 16 + lcol;
            u32 abase2 = (u32)(16384 + r2 * 256);
            u32 aswz2 = (u32)((r2 & 7) << 4);
#pragma unroll
            for (int ks = 0; ks < 4; ++ks) {
                short8 a2 = *(const short8*)(smem + abase2 + ((ks * 64 + kgrp * 16) ^ aswz2));
                acc2[rt][g] = __builtin_amdgcn_mfma_f32_16x16x32_bf16(a2, bw[ks], acc2[rt][g], 0, 0, 0);
            }
        }
    }

    // ---- epilogue: gates + blend; h_new fp32 + transposed bf16 via LDS ----
    float bxz = b_x[hh], bxr = b_x[128 + hh], bxn = b_x[256 + hh];
    float bhz = b_h[hh], bhr = b_h[128 + hh], bhn = b_h[256 + hh];
    float wx0z = W_x[hh], wx0r = W_x[128 + hh], wx0n = W_x[256 + hh];
    float wx1z = W_x[G3 + hh], wx1r = W_x[G3 + 128 + hh], wx1n = W_x[G3 + 256 + hh];
#pragma unroll
    for (int rt = 0; rt < 4; ++rt) {
#pragma unroll
        for (int ri = 0; ri < 4; ++ri) {
            int rl = rt * 16 + kgrp * 4 + ri;
            int i = i0 + rl;
            const float* xp = x + ((size_t)(b * LL + t) * NN + i) * FF;
            float x0 = xp[0], x1 = xp[1];
            float zin = acc2[rt][0][ri] + bhz + fmaf(x0, wx0z, fmaf(x1, wx1z, bxz));
            float rin = acc2[rt][1][ri] + bhr + fmaf(x0, wx0r, fmaf(x1, wx1r, bxr));
            float z = 1.f / (1.f + __expf(-zin));
            float rg = 1.f / (1.f + __expf(-rin));
            float nin = fmaf(rg, acc2[rt][2][ri] + bhn, fmaf(x0, wx0n, fmaf(x1, wx1n, bxn)));
            nin = fmaxf(nin, -40.f);
            float e = __expf(-2.f * nin);
            float n = (1.f - e) / (1.f + e);
            size_t hidx = ((size_t)b * NN + i) * HH + hh;
            float hold = h_old[hidx];
            float hv = fmaf(z, hold - n, n);
            h_new[hidx] = hv;
            *(u16*)(smem + 32768 + hh * 128 + ((2 * rl) ^ ((hh & 7) << 4))) = to_bf16(hv);
        }
    }
    __syncthreads();
    // coalesced copy-out: hT_new[b][n][i0:i0+64]
#pragma unroll
    for (int c = 0; c < 2; ++c) {
        int o = tid * 32 + c * 16;
        int nrow = o >> 7, cbb = o & 127;
        uint4 v = *(const uint4*)(smem + 32768 + nrow * 128 + (cbb ^ ((nrow & 7) << 4)));
        *(uint4*)((char*)(hT_new + ((size_t)b * 128 + nrow) * 1024 + i0) + cbb) = v;
    }
}

// ---- head: out[b,hor,i] = h[b,i,:]@W_head[:,hor]+b_head; 2 thr/row split K ----
__global__ __launch_bounds__(256) void head_kernel(
    const float* __restrict__ hfin, const float* __restrict__ W_head,
    const float* __restrict__ b_head, float* __restrict__ out) {
    __shared__ float wT[HORN * HH];
    int tid = threadIdx.x;
    for (int idx = tid; idx < HORN * HH; idx += 256) {
        int k = idx & 127, hor = idx >> 7;
        wT[hor * 128 + k] = W_head[k * HORN + hor];
    }
    __syncthreads();
    int gtid = blockIdx.x * 256 + tid;
    int row = gtid >> 1, kh = gtid & 1;
    int b = row >> 10, i = row & 1023;
    const float4* hp = (const float4*)(hfin + (size_t)row * 128 + kh * 64);
    float acc[HORN];
#pragma unroll
    for (int hor = 0; hor < HORN; ++hor) acc[hor] = 0.f;
    for (int kk = 0; kk < 16; ++kk) {
        float4 hv = hp[kk];
#pragma unroll
        for (int hor = 0; hor < HORN; ++hor) {
            float4 wv = ((const float4*)wT)[hor * 32 + kh * 16 + kk];
            acc[hor] = fmaf(hv.x, wv.x, fmaf(hv.y, wv.y, fmaf(hv.z, wv.z, fmaf(hv.w, wv.w, acc[hor]))));
        }
    }
#pragma unroll
    for (int hor = 0; hor < HORN; ++hor) {
        float s = acc[hor] + __shfl_xor(acc[hor], 1);
        if (kh == 0) out[((size_t)b * HORN + hor) * NN + i] = s + b_head[hor];
    }
}

extern "C" void kernel_launch(void* const* d_in, const int* in_sizes, int n_in,
                              void* d_out, int out_size, void* d_ws, size_t ws_size,
                              hipStream_t stream) {
    const float* x = (const float*)d_in[0];
    const float* A = (const float*)d_in[1];
    const float* W_x = (const float*)d_in[2];
    const float* b_x = (const float*)d_in[3];
    const float* W_h = (const float*)d_in[4];
    const float* b_h = (const float*)d_in[5];
    const float* W_head = (const float*)d_in[6];
    const float* b_head = (const float*)d_in[7];
    float* out = (float*)d_out;
    char* ws = (char*)d_ws;

    float* hb0 = (float*)(ws + 0);               // 16 MB fp32 h
    float* hb1 = (float*)(ws + 16777216);        // 16 MB
    u16*   hT0 = (u16*)(ws + 33554432);          // 8 MB bf16 h^T
    u16*   hT1 = (u16*)(ws + 41943040);          // 8 MB
    u16*   Abf = (u16*)(ws + 50331648);          // 2 MB bf16 A
    u16*   whT = (u16*)(ws + 52428800);          // 96 KB

    hipMemsetAsync(hb0, 0, 16777216, stream);
    hipMemsetAsync(hT0, 0, 8388608, stream);
    prep_abf<<<1024, 256, 0, stream>>>(A, Abf);
    prep_whT<<<(HH * G3 + 255) / 256, 256, 0, stream>>>(W_h, whT);

    float* ho = hb0; float* hn = hb1;
    u16* hTo = hT0; u16* hTn = hT1;
    for (int t = 0; t < LL; ++t) {
        gru_step<<<512, 512, 0, stream>>>(Abf, hTo, ho, hn, hTn, whT, x, W_x, b_x, b_h, t);
        float* tmp = ho; ho = hn; hn = tmp;
        u16* tmpT = hTo; hTo = hTn; hTn = tmpT;
    }
    head_kernel<<<BB * NN * 2 / 256, 256, 0, stream>>>(ho, W_head, b_head, out);
}

// Round 4
// 343.773 us; speedup vs baseline: 1.9334x; 1.9334x over previous
//
#include <hip/hip_runtime.h>
#include <hip/hip_bf16.h>

#define BB 32
#define LL 12
#define NN 1024
#define FF 2
#define HH 128
#define HORN 12
#define G3 384

typedef unsigned short u16;
typedef unsigned int u32;
typedef unsigned long long u64;
typedef __attribute__((ext_vector_type(8))) short short8;
typedef __attribute__((ext_vector_type(4))) float f32x4;

__device__ __forceinline__ u16 to_bf16(float f) {
    return __builtin_bit_cast(u16, __float2bfloat16(f));
}
__device__ __forceinline__ float bf_to_f(u32 bits) {
    return __builtin_bit_cast(float, bits << 16);
}

// ---- A fp32 [1024][1024] -> bf16 ----
__global__ void prep_abf(const float* __restrict__ A, u16* __restrict__ Abf) {
    int t = blockIdx.x * blockDim.x + threadIdx.x;
    float4 v = ((const float4*)A)[t];
    ushort4 o;
    o.x = to_bf16(v.x); o.y = to_bf16(v.y); o.z = to_bf16(v.z); o.w = to_bf16(v.w);
    ((ushort4*)Abf)[t] = o;
}

// ---- W_h [128][384] fp32 -> W_hT [384][128] bf16 ----
__global__ void prep_whT(const float* __restrict__ W_h, u16* __restrict__ whT) {
    int t = blockIdx.x * blockDim.x + threadIdx.x;
    if (t >= HH * G3) return;
    int c = t / HH, k = t % HH;
    whT[c * HH + k] = to_bf16(W_h[k * G3 + c]);
}

// ---- one GRU step; state = bf16 hT[b][hh][j] only ----
// block: (batch b, rows [i0,i0+64)). 512 thr = 8 waves (2m x 4n of 32x32).
// GEMM1: A[64x1024] @ hT^T -> Ah[64][128]; A+B LDS double-buffered, 1 barrier/chunk.
__global__ __launch_bounds__(512, 4) void gru_step(
    const u16* __restrict__ Abf, const u16* __restrict__ hT_old,
    u16* __restrict__ hT_new, const u16* __restrict__ whT,
    const float* __restrict__ x, const float* __restrict__ W_x,
    const float* __restrict__ b_x, const float* __restrict__ b_h, int t) {
    // LDS: stage buf s in {0,1} @ s*24576: A [64][128B] + B [128][128B]
    // after GEMM1: Ah [64][256B] @ 0 ; T [128][128B] @ 16384  (reuse)
    __shared__ __align__(16) char smem[49152];

    int bid = blockIdx.x;
    int swz = (bid & 7) * 64 + (bid >> 3);  // 64 consecutive per XCD
    int b = swz >> 4;
    int i0 = (swz & 15) * 64;
    int tid = threadIdx.x;
    int w = tid >> 6, lane = tid & 63;
    int lcol = lane & 15, kgrp = lane >> 4;
    int wm = w >> 2, wn = w & 3;

    // ---- staging mapping: per chunk thread moves 3 uint4 (A row, B rows n, n+64) ----
    int s_r = tid >> 3;                    // 0..63
    int s_c = (tid & 7) * 8;               // element col within 64-wide chunk
    const u16* a_src = Abf + (size_t)(i0 + s_r) * 1024 + s_c;
    const u16* b_src = hT_old + (size_t)b * 131072 + (size_t)s_r * 1024 + s_c;
    u32 swb = (u32)((s_c * 2) ^ ((s_r & 7) << 4));
    u32 a_wo = (u32)(s_r * 128) + swb;
    u32 b_wo = 8192u + (u32)(s_r * 128) + swb;   // rows n+64 -> +8192

    // ---- GEMM1 fragment addressing ----
    int ar = wm * 32 + lcol;
    u32 a_base = (u32)(ar * 128), a_swz = (u32)((ar & 7) << 4);
    int bn = wn * 32 + lcol;
    u32 b_base = 8192u + (u32)(bn * 128), b_swz = (u32)((bn & 7) << 4);

    f32x4 acc[2][2] = {{{0.f,0.f,0.f,0.f},{0.f,0.f,0.f,0.f}},
                       {{0.f,0.f,0.f,0.f},{0.f,0.f,0.f,0.f}}};

    // prologue: chunk 0 -> buf0
    uint4 ra = *(const uint4*)a_src;
    uint4 rb0 = *(const uint4*)b_src;
    uint4 rb1 = *(const uint4*)(b_src + 65536);
    *(uint4*)(smem + a_wo) = ra;
    *(uint4*)(smem + b_wo) = rb0;
    *(uint4*)(smem + b_wo + 8192) = rb1;

    for (int c = 0; c < 16; ++c) {
        __syncthreads();
        uint4 na, nb0, nb1;
        bool pf = (c < 15);
        if (pf) {
            int o = (c + 1) * 64;
            na  = *(const uint4*)(a_src + o);
            nb0 = *(const uint4*)(b_src + o);
            nb1 = *(const uint4*)(b_src + o + 65536);
        }
        u32 sb = (u32)((c & 1) * 24576);
#pragma unroll
        for (int ks = 0; ks < 2; ++ks) {
            u32 kb = (u32)(ks * 64 + kgrp * 16);
            short8 af0 = *(const short8*)(smem + sb + a_base + (kb ^ a_swz));
            short8 af1 = *(const short8*)(smem + sb + a_base + 2048 + (kb ^ a_swz));
            short8 bf0 = *(const short8*)(smem + sb + b_base + (kb ^ b_swz));
            short8 bf1 = *(const short8*)(smem + sb + b_base + 2048 + (kb ^ b_swz));
            acc[0][0] = __builtin_amdgcn_mfma_f32_16x16x32_bf16(af0, bf0, acc[0][0], 0, 0, 0);
            acc[0][1] = __builtin_amdgcn_mfma_f32_16x16x32_bf16(af0, bf1, acc[0][1], 0, 0, 0);
            acc[1][0] = __builtin_amdgcn_mfma_f32_16x16x32_bf16(af1, bf0, acc[1][0], 0, 0, 0);
            acc[1][1] = __builtin_amdgcn_mfma_f32_16x16x32_bf16(af1, bf1, acc[1][1], 0, 0, 0);
        }
        if (pf) {
            u32 db = (u32)(((c + 1) & 1) * 24576);
            *(uint4*)(smem + db + a_wo) = na;
            *(uint4*)(smem + db + b_wo) = nb0;
            *(uint4*)(smem + db + b_wo + 8192) = nb1;
        }
    }

    // ---- Ah -> LDS bf16 [64][256B] @0 (chunk15 lived @24576; region 0..24575 idle) ----
#pragma unroll
    for (int mt = 0; mt < 2; ++mt) {
#pragma unroll
        for (int nt = 0; nt < 2; ++nt) {
#pragma unroll
            for (int ri = 0; ri < 4; ++ri) {
                int row = wm * 32 + mt * 16 + kgrp * 4 + ri;
                int col = wn * 32 + nt * 16 + lcol;
                *(u16*)(smem + row * 256 + ((2 * col) ^ ((row & 7) << 4))) = to_bf16(acc[mt][nt][ri]);
            }
        }
    }
    __syncthreads();

    // ---- GEMM2: gates = Ah @ W_h; wave owns hh-tile [w*16, w*16+16) x 3 gates ----
    int hh = w * 16 + lcol;
    short8 bw[3][4];
#pragma unroll
    for (int g = 0; g < 3; ++g)
#pragma unroll
        for (int ks = 0; ks < 4; ++ks)
            bw[g][ks] = *(const short8*)(whT + (size_t)(g * 128 + hh) * 128 + ks * 32 + kgrp * 8);

    f32x4 acc2[4][3];
#pragma unroll
    for (int rt = 0; rt < 4; ++rt)
#pragma unroll
        for (int g = 0; g < 3; ++g) acc2[rt][g] = (f32x4){0.f, 0.f, 0.f, 0.f};

#pragma unroll
    for (int rt = 0; rt < 4; ++rt) {
        int r2 = rt * 16 + lcol;
        u32 ab2 = (u32)(r2 * 256), as2 = (u32)((r2 & 7) << 4);
#pragma unroll
        for (int ks = 0; ks < 4; ++ks) {
            short8 a2 = *(const short8*)(smem + ab2 + ((ks * 64 + kgrp * 16) ^ as2));
            acc2[rt][0] = __builtin_amdgcn_mfma_f32_16x16x32_bf16(a2, bw[0][ks], acc2[rt][0], 0, 0, 0);
            acc2[rt][1] = __builtin_amdgcn_mfma_f32_16x16x32_bf16(a2, bw[1][ks], acc2[rt][1], 0, 0, 0);
            acc2[rt][2] = __builtin_amdgcn_mfma_f32_16x16x32_bf16(a2, bw[2][ks], acc2[rt][2], 0, 0, 0);
        }
    }

    // ---- epilogue: gates + blend (h_old from bf16 hT) ; T-write @16384 ----
    float bxz = b_x[hh], bxr = b_x[128 + hh], bxn = b_x[256 + hh];
    float bhz = b_h[hh], bhr = b_h[128 + hh], bhn = b_h[256 + hh];
    float wx0z = W_x[hh], wx0r = W_x[128 + hh], wx0n = W_x[256 + hh];
    float wx1z = W_x[G3 + hh], wx1r = W_x[G3 + 128 + hh], wx1n = W_x[G3 + 256 + hh];
    const u16* hrow = hT_old + (size_t)b * 131072 + (size_t)hh * 1024 + i0;
#pragma unroll
    for (int rt = 0; rt < 4; ++rt) {
        u64 h4 = *(const u64*)(hrow + rt * 16 + kgrp * 4);
#pragma unroll
        for (int ri = 0; ri < 4; ++ri) {
            int rl = rt * 16 + kgrp * 4 + ri;
            int i = i0 + rl;
            const float* xp = x + ((size_t)(b * LL + t) * NN + i) * FF;
            float x0 = xp[0], x1 = xp[1];
            float zin = acc2[rt][0][ri] + bhz + fmaf(x0, wx0z, fmaf(x1, wx1z, bxz));
            float rin = acc2[rt][1][ri] + bhr + fmaf(x0, wx0r, fmaf(x1, wx1r, bxr));
            float z = 1.f / (1.f + __expf(-zin));
            float rg = 1.f / (1.f + __expf(-rin));
            float nin = fmaf(rg, acc2[rt][2][ri] + bhn, fmaf(x0, wx0n, fmaf(x1, wx1n, bxn)));
            nin = fmaxf(nin, -40.f);
            float e = __expf(-2.f * nin);
            float n = (1.f - e) / (1.f + e);
            float hold = bf_to_f((u32)((h4 >> (16 * ri)) & 0xffffu));
            float hv = fmaf(z, hold - n, n);
            *(u16*)(smem + 16384 + hh * 128 + ((2 * rl) ^ ((hh & 7) << 4))) = to_bf16(hv);
        }
    }
    __syncthreads();
    // coalesced copy-out: hT_new[b][n][i0:i0+64]
#pragma unroll
    for (int c2 = 0; c2 < 2; ++c2) {
        int o = tid * 32 + c2 * 16;
        int nrow = o >> 7, cbb = o & 127;
        uint4 v = *(const uint4*)(smem + 16384 + nrow * 128 + (cbb ^ ((nrow & 7) << 4)));
        *(uint4*)((char*)(hT_new + ((size_t)b * 128 + nrow) * 1024 + i0) + cbb) = v;
    }
}

// ---- head: out[b,hor,i] = sum_hh hT[b][hh][i] * W_head[hh,hor] + b_head ----
__global__ __launch_bounds__(256) void head_kernel(
    const u16* __restrict__ hT, const float* __restrict__ W_head,
    const float* __restrict__ b_head, float* __restrict__ out) {
    __shared__ float wl[HH * HORN];
    __shared__ float bl[HORN];
    int tid = threadIdx.x;
    for (int ix = tid; ix < HH * HORN; ix += 256) wl[ix] = W_head[ix];
    if (tid < HORN) bl[tid] = b_head[tid];
    __syncthreads();
    int blk = blockIdx.x;
    int b = blk >> 2;
    int i = (blk & 3) * 256 + tid;
    const u16* hp = hT + (size_t)b * 131072 + i;
    float acc[HORN];
#pragma unroll
    for (int hor = 0; hor < HORN; ++hor) acc[hor] = bl[hor];
    for (int hh = 0; hh < HH; ++hh) {
        float hv = bf_to_f((u32)hp[hh * 1024]);
#pragma unroll
        for (int hor = 0; hor < HORN; ++hor)
            acc[hor] = fmaf(hv, wl[hh * HORN + hor], acc[hor]);
    }
#pragma unroll
    for (int hor = 0; hor < HORN; ++hor)
        out[((size_t)b * HORN + hor) * NN + i] = acc[hor];
}

extern "C" void kernel_launch(void* const* d_in, const int* in_sizes, int n_in,
                              void* d_out, int out_size, void* d_ws, size_t ws_size,
                              hipStream_t stream) {
    const float* x = (const float*)d_in[0];
    const float* A = (const float*)d_in[1];
    const float* W_x = (const float*)d_in[2];
    const float* b_x = (const float*)d_in[3];
    const float* W_h = (const float*)d_in[4];
    const float* b_h = (const float*)d_in[5];
    const float* W_head = (const float*)d_in[6];
    const float* b_head = (const float*)d_in[7];
    float* out = (float*)d_out;
    char* ws = (char*)d_ws;

    u16* hT0 = (u16*)(ws + 0);               // 8 MB bf16 hT [b][hh][j]
    u16* hT1 = (u16*)(ws + 8388608);         // 8 MB
    u16* Abf = (u16*)(ws + 16777216);        // 2 MB bf16 A
    u16* whT = (u16*)(ws + 18874368);        // 96 KB

    hipMemsetAsync(hT0, 0, 8388608, stream);
    prep_abf<<<1024, 256, 0, stream>>>(A, Abf);
    prep_whT<<<(HH * G3 + 255) / 256, 256, 0, stream>>>(W_h, whT);

    u16* hTo = hT0; u16* hTn = hT1;
    for (int t = 0; t < LL; ++t) {
        gru_step<<<512, 512, 0, stream>>>(Abf, hTo, hTn, whT, x, W_x, b_x, b_h, t);
        u16* tmp = hTo; hTo = hTn; hTn = tmp;
    }
    head_kernel<<<BB * 4, 256, 0, stream>>>(hTo, W_head, b_head, out);
}

// Round 5
// 324.551 us; speedup vs baseline: 2.0479x; 1.0592x over previous
//
#include <hip/hip_runtime.h>
#include <hip/hip_bf16.h>

#define BB 32
#define LL 12
#define NN 1024
#define HH 128
#define HORN 12
#define G3 384

typedef unsigned short u16;
typedef unsigned int u32;
typedef unsigned long long u64;
typedef __attribute__((ext_vector_type(8))) short short8;
typedef __attribute__((ext_vector_type(4))) float f32x4;

__device__ __forceinline__ u16 to_bf16(float f) {
    return __builtin_bit_cast(u16, __float2bfloat16(f));
}
__device__ __forceinline__ float bf_to_f(u32 bits) {
    return __builtin_bit_cast(float, bits << 16);
}
// async global->LDS, 16B per lane; lds ptr is wave-uniform base, lane i lands at base+i*16
__device__ __forceinline__ void gl16(const u16* g, char* l) {
    __builtin_amdgcn_global_load_lds((const __attribute__((address_space(1))) u32*)g,
                                     (__attribute__((address_space(3))) u32*)l, 16, 0, 0);
}

// ---- A fp32 [1024][1024] -> bf16 ----
__global__ void prep_abf(const float* __restrict__ A, u16* __restrict__ Abf) {
    int t = blockIdx.x * blockDim.x + threadIdx.x;
    float4 v = ((const float4*)A)[t];
    ushort4 o;
    o.x = to_bf16(v.x); o.y = to_bf16(v.y); o.z = to_bf16(v.z); o.w = to_bf16(v.w);
    ((ushort4*)Abf)[t] = o;
}

// ---- W_h [128][384] fp32 -> W_hT [384][128] bf16 ----
__global__ void prep_whT(const float* __restrict__ W_h, u16* __restrict__ whT) {
    int t = blockIdx.x * blockDim.x + threadIdx.x;
    if (t >= HH * G3) return;
    int c = t / HH, k = t % HH;
    whT[c * HH + k] = to_bf16(W_h[k * G3 + c]);
}

// ---- one GRU step; state = bf16 hT[b][hh][j] ----
// block: (batch b, rows [i0,i0+64)). 256 thr = 4 waves (2m x 2n of 32x64 tiles).
// GEMM1 staging via global_load_lds (linear dest, pre-swizzled src), dbuf, 1 barrier/chunk.
template <bool FIRST>
__global__ __launch_bounds__(256, 2) void gru_step(
    const u16* __restrict__ Abf, const u16* __restrict__ hT_old,
    u16* __restrict__ hT_new, const u16* __restrict__ whT,
    const float* __restrict__ x, const float* __restrict__ W_x,
    const float* __restrict__ b_x, const float* __restrict__ b_h, int t) {
    // LDS: stage buf s@s*24576: A[64][128B]@+0, B[128][128B]@+8192 | Ah[64][256B]@49152 | T[128][128B]@0 (reuse)
    __shared__ __align__(16) char smem[65536];

    int bid = blockIdx.x;
    int swz = (bid & 7) * 64 + (bid >> 3);  // 64 consecutive per XCD -> 4 batches/XCD
    int b = swz >> 4;
    int i0 = (swz & 15) * 64;
    int tid = threadIdx.x;
    int w = tid >> 6, lane = tid & 63;
    int lcol = lane & 15, kgrp = lane >> 4;
    int wm = w >> 1, wn = w & 1;
    u32 swzl = (u32)((lcol & 7) << 4);

    // ---- fragment base addrs (rows ar..ar+16 / bn..bn+48 share swizzle bits: &7 == lcol&7) ----
    u32 a_b = (u32)((wm * 32 + lcol) * 128);
    u32 b_b = (u32)(8192 + (wn * 64 + lcol) * 128);

    f32x4 acc[2][4];
#pragma unroll
    for (int m = 0; m < 2; ++m)
#pragma unroll
        for (int n = 0; n < 4; ++n) acc[m][n] = (f32x4){0.f, 0.f, 0.f, 0.f};

    if (!FIRST) {
        // ---- staging mapping: per-lane global src (col-slot inverse-swizzled), uniform LDS dest ----
        int lr3 = lane >> 3, lc8 = lane & 7;
        const u16* ag[2]; u32 al[2];
        const u16* bg[4]; u32 bl[4];
#pragma unroll
        for (int q = 0; q < 2; ++q) {
            int r = w * 16 + q * 8 + lr3;
            ag[q] = Abf + (size_t)(i0 + r) * 1024 + (lc8 ^ (r & 7)) * 8;
            al[q] = (u32)(w * 2048 + q * 1024);
        }
#pragma unroll
        for (int q = 0; q < 4; ++q) {
            int r = w * 32 + q * 8 + lr3;
            bg[q] = hT_old + (size_t)b * 131072 + (size_t)r * 1024 + (lc8 ^ (r & 7)) * 8;
            bl[q] = (u32)(8192 + w * 4096 + q * 1024);
        }

        // prologue: chunk 0 -> buf0
#pragma unroll
        for (int q = 0; q < 2; ++q) gl16(ag[q], smem + al[q]);
#pragma unroll
        for (int q = 0; q < 4; ++q) gl16(bg[q], smem + bl[q]);
        __syncthreads();

        for (int c = 0; c < 16; ++c) {
            u32 sb = (u32)((c & 1) * 24576);
            if (c < 15) {  // issue next chunk's DMA first; hides under MFMA, drained by barrier
                int o = (c + 1) * 64;
                u32 db = (u32)(((c + 1) & 1) * 24576);
#pragma unroll
                for (int q = 0; q < 2; ++q) gl16(ag[q] + o, smem + db + al[q]);
#pragma unroll
                for (int q = 0; q < 4; ++q) gl16(bg[q] + o, smem + db + bl[q]);
            }
#pragma unroll
            for (int ks = 0; ks < 2; ++ks) {
                u32 kb = ((u32)(ks * 64 + kgrp * 16)) ^ swzl;
                short8 a0 = *(const short8*)(smem + sb + a_b + kb);
                short8 a1 = *(const short8*)(smem + sb + a_b + 2048 + kb);
                short8 b0 = *(const short8*)(smem + sb + b_b + kb);
                short8 b1 = *(const short8*)(smem + sb + b_b + 2048 + kb);
                short8 b2 = *(const short8*)(smem + sb + b_b + 4096 + kb);
                short8 b3 = *(const short8*)(smem + sb + b_b + 6144 + kb);
                acc[0][0] = __builtin_amdgcn_mfma_f32_16x16x32_bf16(a0, b0, acc[0][0], 0, 0, 0);
                acc[0][1] = __builtin_amdgcn_mfma_f32_16x16x32_bf16(a0, b1, acc[0][1], 0, 0, 0);
                acc[0][2] = __builtin_amdgcn_mfma_f32_16x16x32_bf16(a0, b2, acc[0][2], 0, 0, 0);
                acc[0][3] = __builtin_amdgcn_mfma_f32_16x16x32_bf16(a0, b3, acc[0][3], 0, 0, 0);
                acc[1][0] = __builtin_amdgcn_mfma_f32_16x16x32_bf16(a1, b0, acc[1][0], 0, 0, 0);
                acc[1][1] = __builtin_amdgcn_mfma_f32_16x16x32_bf16(a1, b1, acc[1][1], 0, 0, 0);
                acc[1][2] = __builtin_amdgcn_mfma_f32_16x16x32_bf16(a1, b2, acc[1][2], 0, 0, 0);
                acc[1][3] = __builtin_amdgcn_mfma_f32_16x16x32_bf16(a1, b3, acc[1][3], 0, 0, 0);
            }
            __syncthreads();
        }
    }

    // ---- Ah -> LDS bf16 [64][256B] @49152 ----
#pragma unroll
    for (int m = 0; m < 2; ++m)
#pragma unroll
        for (int n = 0; n < 4; ++n)
#pragma unroll
            for (int ri = 0; ri < 4; ++ri) {
                int row = wm * 32 + m * 16 + kgrp * 4 + ri;
                int col = wn * 64 + n * 16 + lcol;
                *(u16*)(smem + 49152 + row * 256 + (((u32)(2 * col)) ^ ((u32)(row & 7) << 4))) =
                    to_bf16(acc[m][n][ri]);
            }
    __syncthreads();

    // ---- GEMM2 + epilogue, per hh-subtile (wave covers hh = w*32+sub*16+lcol) ----
#pragma unroll
    for (int sub = 0; sub < 2; ++sub) {
        int hh = w * 32 + sub * 16 + lcol;
        short8 bw[3][4];
#pragma unroll
        for (int g = 0; g < 3; ++g)
#pragma unroll
            for (int ks = 0; ks < 4; ++ks)
                bw[g][ks] = *(const short8*)(whT + (size_t)(g * 128 + hh) * 128 + ks * 32 + kgrp * 8);

        f32x4 acc2[4][3];
#pragma unroll
        for (int rt = 0; rt < 4; ++rt)
#pragma unroll
            for (int g = 0; g < 3; ++g) acc2[rt][g] = (f32x4){0.f, 0.f, 0.f, 0.f};

#pragma unroll
        for (int rt = 0; rt < 4; ++rt) {
            u32 ab2 = (u32)(49152 + (rt * 16 + lcol) * 256);
#pragma unroll
            for (int ks = 0; ks < 4; ++ks) {
                short8 a2 = *(const short8*)(smem + ab2 + (((u32)(ks * 64 + kgrp * 16)) ^ swzl));
                acc2[rt][0] = __builtin_amdgcn_mfma_f32_16x16x32_bf16(a2, bw[0][ks], acc2[rt][0], 0, 0, 0);
                acc2[rt][1] = __builtin_amdgcn_mfma_f32_16x16x32_bf16(a2, bw[1][ks], acc2[rt][1], 0, 0, 0);
                acc2[rt][2] = __builtin_amdgcn_mfma_f32_16x16x32_bf16(a2, bw[2][ks], acc2[rt][2], 0, 0, 0);
            }
        }

        float bxz = b_x[hh], bxr = b_x[128 + hh], bxn = b_x[256 + hh];
        float bhz = b_h[hh], bhr = b_h[128 + hh], bhn = b_h[256 + hh];
        float wx0z = W_x[hh], wx0r = W_x[128 + hh], wx0n = W_x[256 + hh];
        float wx1z = W_x[G3 + hh], wx1r = W_x[G3 + 128 + hh], wx1n = W_x[G3 + 256 + hh];
        const u16* hrow = hT_old + (size_t)b * 131072 + (size_t)hh * 1024 + i0;
#pragma unroll
        for (int rt = 0; rt < 4; ++rt) {
            u64 h4 = 0;
            if (!FIRST) h4 = *(const u64*)(hrow + rt * 16 + kgrp * 4);
#pragma unroll
            for (int ri = 0; ri < 4; ++ri) {
                int rl = rt * 16 + kgrp * 4 + ri;
                int i = i0 + rl;
                const float* xp = x + ((size_t)(b * LL + t) * NN + i) * 2;
                float x0 = xp[0], x1 = xp[1];
                float zin = acc2[rt][0][ri] + bhz + fmaf(x0, wx0z, fmaf(x1, wx1z, bxz));
                float rin = acc2[rt][1][ri] + bhr + fmaf(x0, wx0r, fmaf(x1, wx1r, bxr));
                float z = 1.f / (1.f + __expf(-zin));
                float rg = 1.f / (1.f + __expf(-rin));
                float nin = fmaf(rg, acc2[rt][2][ri] + bhn, fmaf(x0, wx0n, fmaf(x1, wx1n, bxn)));
                nin = fmaxf(nin, -40.f);
                float e = __expf(-2.f * nin);
                float n = (1.f - e) / (1.f + e);
                float hold = bf_to_f((u32)((h4 >> (16 * ri)) & 0xffffu));
                float hv = fmaf(z, hold - n, n);
                *(u16*)(smem + hh * 128 + (((u32)(2 * rl)) ^ ((u32)(hh & 7) << 4))) = to_bf16(hv);
            }
        }
    }
    __syncthreads();
    // coalesced copy-out: hT_new[b][n][i0:i0+64]
#pragma unroll
    for (int c2 = 0; c2 < 4; ++c2) {
        int o = c2 * 4096 + tid * 16;
        int nr = o >> 7, cb = o & 127;
        uint4 v = *(const uint4*)(smem + nr * 128 + (((u32)cb) ^ ((u32)(nr & 7) << 4)));
        *(uint4*)((char*)(hT_new + (size_t)b * 131072 + (size_t)nr * 1024 + i0) + cb) = v;
    }
}

// ---- head: out[b,hor,i] = sum_hh hT[b][hh][i] * W_head[hh,hor] + b_head ----
__global__ __launch_bounds__(256) void head_kernel(
    const u16* __restrict__ hT, const float* __restrict__ W_head,
    const float* __restrict__ b_head, float* __restrict__ out) {
    __shared__ float wl[HH * HORN];
    __shared__ float bl[HORN];
    int tid = threadIdx.x;
    for (int ix = tid; ix < HH * HORN; ix += 256) wl[ix] = W_head[ix];
    if (tid < HORN) bl[tid] = b_head[tid];
    __syncthreads();
    int blk = blockIdx.x;
    int b = blk >> 2;
    int i = (blk & 3) * 256 + tid;
    const u16* hp = hT + (size_t)b * 131072 + i;
    float acc[HORN];
#pragma unroll
    for (int hor = 0; hor < HORN; ++hor) acc[hor] = bl[hor];
    for (int hh = 0; hh < HH; ++hh) {
        float hv = bf_to_f((u32)hp[hh * 1024]);
#pragma unroll
        for (int hor = 0; hor < HORN; ++hor)
            acc[hor] = fmaf(hv, wl[hh * HORN + hor], acc[hor]);
    }
#pragma unroll
    for (int hor = 0; hor < HORN; ++hor)
        out[((size_t)b * HORN + hor) * NN + i] = acc[hor];
}

extern "C" void kernel_launch(void* const* d_in, const int* in_sizes, int n_in,
                              void* d_out, int out_size, void* d_ws, size_t ws_size,
                              hipStream_t stream) {
    const float* x = (const float*)d_in[0];
    const float* A = (const float*)d_in[1];
    const float* W_x = (const float*)d_in[2];
    const float* b_x = (const float*)d_in[3];
    const float* W_h = (const float*)d_in[4];
    const float* b_h = (const float*)d_in[5];
    const float* W_head = (const float*)d_in[6];
    const float* b_head = (const float*)d_in[7];
    float* out = (float*)d_out;
    char* ws = (char*)d_ws;

    u16* hT0 = (u16*)(ws + 0);               // 8 MB bf16 hT [b][hh][j]
    u16* hT1 = (u16*)(ws + 8388608);         // 8 MB
    u16* Abf = (u16*)(ws + 16777216);        // 2 MB bf16 A
    u16* whT = (u16*)(ws + 18874368);        // 96 KB

    prep_abf<<<1024, 256, 0, stream>>>(A, Abf);
    prep_whT<<<(HH * G3 + 255) / 256, 256, 0, stream>>>(W_h, whT);

    // t = 0: h_old == 0, no staging/GEMM1/blend-read needed
    gru_step<true><<<512, 256, 0, stream>>>(Abf, hT1, hT0, whT, x, W_x, b_x, b_h, 0);
    u16* hTo = hT0; u16* hTn = hT1;
    for (int t = 1; t < LL; ++t) {
        gru_step<false><<<512, 256, 0, stream>>>(Abf, hTo, hTn, whT, x, W_x, b_x, b_h, t);
        u16* tmp = hTo; hTo = hTn; hTn = tmp;
    }
    head_kernel<<<BB * 4, 256, 0, stream>>>(hTo, W_head, b_head, out);
}

// Round 6
// 306.331 us; speedup vs baseline: 2.1698x; 1.0595x over previous
//
#include <hip/hip_runtime.h>
#include <hip/hip_bf16.h>

#define BB 32
#define LL 12
#define NN 1024
#define HH 128
#define HORN 12
#define G3 384

typedef unsigned short u16;
typedef unsigned int u32;
typedef unsigned long long u64;
typedef __attribute__((ext_vector_type(8))) short short8;
typedef __attribute__((ext_vector_type(4))) float f32x4;

__device__ __forceinline__ u16 to_bf16(float f) {
    return __builtin_bit_cast(u16, __float2bfloat16(f));
}
__device__ __forceinline__ float bf_to_f(u32 bits) {
    return __builtin_bit_cast(float, bits << 16);
}
// async global->LDS, 16B per lane; lds ptr is wave-uniform base, lane i lands at base+i*16
__device__ __forceinline__ void gl16(const u16* g, char* l) {
    __builtin_amdgcn_global_load_lds((const __attribute__((address_space(1))) u32*)g,
                                     (__attribute__((address_space(3))) u32*)l, 16, 0, 0);
}

// ---- A fp32 [1024][1024] -> bf16 ----
__global__ void prep_abf(const float* __restrict__ A, u16* __restrict__ Abf) {
    int t = blockIdx.x * blockDim.x + threadIdx.x;
    float4 v = ((const float4*)A)[t];
    ushort4 o;
    o.x = to_bf16(v.x); o.y = to_bf16(v.y); o.z = to_bf16(v.z); o.w = to_bf16(v.w);
    ((ushort4*)Abf)[t] = o;
}

// ---- W_h [128][384] fp32 -> W_hT [384][128] bf16 ----
__global__ void prep_whT(const float* __restrict__ W_h, u16* __restrict__ whT) {
    int t = blockIdx.x * blockDim.x + threadIdx.x;
    if (t >= HH * G3) return;
    int c = t / HH, k = t % HH;
    whT[c * HH + k] = to_bf16(W_h[k * G3 + c]);
}

// ---- one GRU step; state = bf16 hT[b][hh][j] ----
// block: (batch b, rows [i0,i0+64)). 256 thr = 4 waves (2m x 2n of 32x64 tiles).
// GEMM1: counted-vmcnt pipeline (T4): 2 LDS bufs, 2 raw barriers/chunk, vmcnt(6),
// loads for chunk c+2 issued as chunk c ends -> ~1.5 chunks of latency hiding.
template <bool FIRST>
__global__ __launch_bounds__(256, 2) void gru_step(
    const u16* __restrict__ Abf, const u16* __restrict__ hT_old,
    u16* __restrict__ hT_new, const u16* __restrict__ whT,
    const float* __restrict__ x, const float* __restrict__ W_x,
    const float* __restrict__ b_x, const float* __restrict__ b_h, int t) {
    // LDS: stage buf s@s*24576: A[64][128B]@+0, B[128][128B]@+8192 | Ah[64][256B]@49152 | T@0 (reuse)
    __shared__ __align__(16) char smem[65536];

    int bid = blockIdx.x;
    int swz = (bid & 7) * 64 + (bid >> 3);  // 64 consecutive per XCD -> 4 batches/XCD
    int b = swz >> 4;
    int i0 = (swz & 15) * 64;
    int tid = threadIdx.x;
    int w = tid >> 6, lane = tid & 63;
    int lcol = lane & 15, kgrp = lane >> 4;
    int wm = w >> 1, wn = w & 1;
    u32 swzl = (u32)((lcol & 7) << 4);

    u32 a_b = (u32)((wm * 32 + lcol) * 128);
    u32 b_b = (u32)(8192 + (wn * 64 + lcol) * 128);

    f32x4 acc[2][4];
#pragma unroll
    for (int m = 0; m < 2; ++m)
#pragma unroll
        for (int n = 0; n < 4; ++n) acc[m][n] = (f32x4){0.f, 0.f, 0.f, 0.f};

    u64 hreg[2][4] = {};  // blend values hT_old[b][hh][i0+..], grabbed from LDS in chunk i0/64

    if (!FIRST) {
        // staging mapping: per-lane global src (col-granule inverse-swizzled), uniform LDS dest
        int lr3 = lane >> 3, lc8 = lane & 7;
        const u16* ag[2]; u32 al[2];
        const u16* bg[4]; u32 bl[4];
#pragma unroll
        for (int q = 0; q < 2; ++q) {
            int r = w * 16 + q * 8 + lr3;
            ag[q] = Abf + (size_t)(i0 + r) * 1024 + (lc8 ^ (r & 7)) * 8;
            al[q] = (u32)(w * 2048 + q * 1024);
        }
#pragma unroll
        for (int q = 0; q < 4; ++q) {
            int r = w * 32 + q * 8 + lr3;
            bg[q] = hT_old + (size_t)b * 131072 + (size_t)r * 1024 + (lc8 ^ (r & 7)) * 8;
            bl[q] = (u32)(8192 + w * 4096 + q * 1024);
        }

        // prologue: chunks 0 -> buf0, 1 -> buf1 (12 loads in flight)
#pragma unroll
        for (int q = 0; q < 2; ++q) gl16(ag[q], smem + al[q]);
#pragma unroll
        for (int q = 0; q < 4; ++q) gl16(bg[q], smem + bl[q]);
#pragma unroll
        for (int q = 0; q < 2; ++q) gl16(ag[q] + 64, smem + 24576 + al[q]);
#pragma unroll
        for (int q = 0; q < 4; ++q) gl16(bg[q] + 64, smem + 24576 + bl[q]);

        int cstar = i0 >> 6;
        for (int c = 0; c < 16; ++c) {
            u32 sb = (u32)((c & 1) * 24576);
            if (c < 15) asm volatile("s_waitcnt vmcnt(6)" ::: "memory");
            else        asm volatile("s_waitcnt vmcnt(0)" ::: "memory");
            __builtin_amdgcn_s_barrier();
            __builtin_amdgcn_sched_barrier(0);

            if (c == cstar) {  // snapshot blend values for rows i0..i0+64 (cols of this B chunk)
#pragma unroll
                for (int sub = 0; sub < 2; ++sub) {
                    int hh = w * 32 + sub * 16 + lcol;
                    u32 rb = sb + 8192u + (u32)(hh * 128);
                    u32 sw = (u32)((hh & 7) << 4);
#pragma unroll
                    for (int rt = 0; rt < 4; ++rt)
                        hreg[sub][rt] = *(const u64*)(smem + rb + (((u32)(rt * 32 + kgrp * 8)) ^ sw));
                }
                asm volatile("s_waitcnt lgkmcnt(0)" ::: "memory");
                __builtin_amdgcn_sched_barrier(0);
            }

            __builtin_amdgcn_s_setprio(1);
#pragma unroll
            for (int ks = 0; ks < 2; ++ks) {
                u32 kb = ((u32)(ks * 64 + kgrp * 16)) ^ swzl;
                short8 a0 = *(const short8*)(smem + sb + a_b + kb);
                short8 a1 = *(const short8*)(smem + sb + a_b + 2048 + kb);
                short8 b0 = *(const short8*)(smem + sb + b_b + kb);
                short8 b1 = *(const short8*)(smem + sb + b_b + 2048 + kb);
                short8 b2 = *(const short8*)(smem + sb + b_b + 4096 + kb);
                short8 b3 = *(const short8*)(smem + sb + b_b + 6144 + kb);
                acc[0][0] = __builtin_amdgcn_mfma_f32_16x16x32_bf16(a0, b0, acc[0][0], 0, 0, 0);
                acc[0][1] = __builtin_amdgcn_mfma_f32_16x16x32_bf16(a0, b1, acc[0][1], 0, 0, 0);
                acc[0][2] = __builtin_amdgcn_mfma_f32_16x16x32_bf16(a0, b2, acc[0][2], 0, 0, 0);
                acc[0][3] = __builtin_amdgcn_mfma_f32_16x16x32_bf16(a0, b3, acc[0][3], 0, 0, 0);
                acc[1][0] = __builtin_amdgcn_mfma_f32_16x16x32_bf16(a1, b0, acc[1][0], 0, 0, 0);
                acc[1][1] = __builtin_amdgcn_mfma_f32_16x16x32_bf16(a1, b1, acc[1][1], 0, 0, 0);
                acc[1][2] = __builtin_amdgcn_mfma_f32_16x16x32_bf16(a1, b2, acc[1][2], 0, 0, 0);
                acc[1][3] = __builtin_amdgcn_mfma_f32_16x16x32_bf16(a1, b3, acc[1][3], 0, 0, 0);
            }
            __builtin_amdgcn_s_setprio(0);
            asm volatile("" ::: "memory");
            __builtin_amdgcn_s_barrier();     // all waves done reading buf[c&1]
            if (c < 14) {                      // issue chunk c+2 into the freed buffer
                int o = (c + 2) * 64;
#pragma unroll
                for (int q = 0; q < 2; ++q) gl16(ag[q] + o, smem + sb + al[q]);
#pragma unroll
                for (int q = 0; q < 4; ++q) gl16(bg[q] + o, smem + sb + bl[q]);
            }
        }
        asm volatile("" ::: "memory");
        __builtin_amdgcn_s_barrier();
    }

    // ---- Ah -> LDS bf16 [64][256B] @49152 ----
#pragma unroll
    for (int m = 0; m < 2; ++m)
#pragma unroll
        for (int n = 0; n < 4; ++n)
#pragma unroll
            for (int ri = 0; ri < 4; ++ri) {
                int row = wm * 32 + m * 16 + kgrp * 4 + ri;
                int col = wn * 64 + n * 16 + lcol;
                *(u16*)(smem + 49152 + row * 256 + (((u32)(2 * col)) ^ ((u32)(row & 7) << 4))) =
                    to_bf16(acc[m][n][ri]);
            }
    __syncthreads();

    // ---- GEMM2 + epilogue, per hh-subtile (wave covers hh = w*32+sub*16+lcol) ----
#pragma unroll
    for (int sub = 0; sub < 2; ++sub) {
        int hh = w * 32 + sub * 16 + lcol;
        short8 bw[3][4];
#pragma unroll
        for (int g = 0; g < 3; ++g)
#pragma unroll
            for (int ks = 0; ks < 4; ++ks)
                bw[g][ks] = *(const short8*)(whT + (size_t)(g * 128 + hh) * 128 + ks * 32 + kgrp * 8);

        f32x4 acc2[4][3];
#pragma unroll
        for (int rt = 0; rt < 4; ++rt)
#pragma unroll
            for (int g = 0; g < 3; ++g) acc2[rt][g] = (f32x4){0.f, 0.f, 0.f, 0.f};

        __builtin_amdgcn_s_setprio(1);
#pragma unroll
        for (int rt = 0; rt < 4; ++rt) {
            u32 ab2 = (u32)(49152 + (rt * 16 + lcol) * 256);
#pragma unroll
            for (int ks = 0; ks < 4; ++ks) {
                short8 a2 = *(const short8*)(smem + ab2 + (((u32)(ks * 64 + kgrp * 16)) ^ swzl));
                acc2[rt][0] = __builtin_amdgcn_mfma_f32_16x16x32_bf16(a2, bw[0][ks], acc2[rt][0], 0, 0, 0);
                acc2[rt][1] = __builtin_amdgcn_mfma_f32_16x16x32_bf16(a2, bw[1][ks], acc2[rt][1], 0, 0, 0);
                acc2[rt][2] = __builtin_amdgcn_mfma_f32_16x16x32_bf16(a2, bw[2][ks], acc2[rt][2], 0, 0, 0);
            }
        }
        __builtin_amdgcn_s_setprio(0);

        float bxz = b_x[hh], bxr = b_x[128 + hh], bxn = b_x[256 + hh];
        float bhz = b_h[hh], bhr = b_h[128 + hh], bhn = b_h[256 + hh];
        float wx0z = W_x[hh], wx0r = W_x[128 + hh], wx0n = W_x[256 + hh];
        float wx1z = W_x[G3 + hh], wx1r = W_x[G3 + 128 + hh], wx1n = W_x[G3 + 256 + hh];
#pragma unroll
        for (int rt = 0; rt < 4; ++rt) {
            u64 h4 = hreg[sub][rt];
#pragma unroll
            for (int ri = 0; ri < 4; ++ri) {
                int rl = rt * 16 + kgrp * 4 + ri;
                int i = i0 + rl;
                const float* xp = x + ((size_t)(b * LL + t) * NN + i) * 2;
                float x0 = xp[0], x1 = xp[1];
                float zin = acc2[rt][0][ri] + bhz + fmaf(x0, wx0z, fmaf(x1, wx1z, bxz));
                float rin = acc2[rt][1][ri] + bhr + fmaf(x0, wx0r, fmaf(x1, wx1r, bxr));
                float z = 1.f / (1.f + __expf(-zin));
                float rg = 1.f / (1.f + __expf(-rin));
                float nin = fmaf(rg, acc2[rt][2][ri] + bhn, fmaf(x0, wx0n, fmaf(x1, wx1n, bxn)));
                nin = fmaxf(nin, -40.f);
                float e = __expf(-2.f * nin);
                float n = (1.f - e) / (1.f + e);
                float hold = bf_to_f((u32)((h4 >> (16 * ri)) & 0xffffu));
                float hv = fmaf(z, hold - n, n);
                *(u16*)(smem + hh * 128 + (((u32)(2 * rl)) ^ ((u32)(hh & 7) << 4))) = to_bf16(hv);
            }
        }
    }
    __syncthreads();
    // coalesced copy-out: hT_new[b][n][i0:i0+64]
#pragma unroll
    for (int c2 = 0; c2 < 4; ++c2) {
        int o = c2 * 4096 + tid * 16;
        int nr = o >> 7, cb = o & 127;
        uint4 v = *(const uint4*)(smem + nr * 128 + (((u32)cb) ^ ((u32)(nr & 7) << 4)));
        *(uint4*)((char*)(hT_new + (size_t)b * 131072 + (size_t)nr * 1024 + i0) + cb) = v;
    }
}

// ---- head: out[b,hor,i] = sum_hh hT[b][hh][i] * W_head[hh,hor] + b_head ----
__global__ __launch_bounds__(256) void head_kernel(
    const u16* __restrict__ hT, const float* __restrict__ W_head,
    const float* __restrict__ b_head, float* __restrict__ out) {
    __shared__ float wl[HH * HORN];
    __shared__ float bl[HORN];
    int tid = threadIdx.x;
    for (int ix = tid; ix < HH * HORN; ix += 256) wl[ix] = W_head[ix];
    if (tid < HORN) bl[tid] = b_head[tid];
    __syncthreads();
    int blk = blockIdx.x;
    int b = blk >> 2;
    int i = (blk & 3) * 256 + tid;
    const u16* hp = hT + (size_t)b * 131072 + i;
    float acc[HORN];
#pragma unroll
    for (int hor = 0; hor < HORN; ++hor) acc[hor] = bl[hor];
    for (int hh = 0; hh < HH; ++hh) {
        float hv = bf_to_f((u32)hp[hh * 1024]);
#pragma unroll
        for (int hor = 0; hor < HORN; ++hor)
            acc[hor] = fmaf(hv, wl[hh * HORN + hor], acc[hor]);
    }
#pragma unroll
    for (int hor = 0; hor < HORN; ++hor)
        out[((size_t)b * HORN + hor) * NN + i] = acc[hor];
}

extern "C" void kernel_launch(void* const* d_in, const int* in_sizes, int n_in,
                              void* d_out, int out_size, void* d_ws, size_t ws_size,
                              hipStream_t stream) {
    const float* x = (const float*)d_in[0];
    const float* A = (const float*)d_in[1];
    const float* W_x = (const float*)d_in[2];
    const float* b_x = (const float*)d_in[3];
    const float* W_h = (const float*)d_in[4];
    const float* b_h = (const float*)d_in[5];
    const float* W_head = (const float*)d_in[6];
    const float* b_head = (const float*)d_in[7];
    float* out = (float*)d_out;
    char* ws = (char*)d_ws;

    u16* hT0 = (u16*)(ws + 0);               // 8 MB bf16 hT [b][hh][j]
    u16* hT1 = (u16*)(ws + 8388608);         // 8 MB
    u16* Abf = (u16*)(ws + 16777216);        // 2 MB bf16 A
    u16* whT = (u16*)(ws + 18874368);        // 96 KB

    prep_abf<<<1024, 256, 0, stream>>>(A, Abf);
    prep_whT<<<(HH * G3 + 255) / 256, 256, 0, stream>>>(W_h, whT);

    // t = 0: h_old == 0, no staging/GEMM1/blend-read needed
    gru_step<true><<<512, 256, 0, stream>>>(Abf, hT1, hT0, whT, x, W_x, b_x, b_h, 0);
    u16* hTo = hT0; u16* hTn = hT1;
    for (int t = 1; t < LL; ++t) {
        gru_step<false><<<512, 256, 0, stream>>>(Abf, hTo, hTn, whT, x, W_x, b_x, b_h, t);
        u16* tmp = hTo; hTo = hTn; hTn = tmp;
    }
    head_kernel<<<BB * 4, 256, 0, stream>>>(hTo, W_head, b_head, out);
}